// Round 1
// 788.930 us; speedup vs baseline: 1.0076x; 1.0076x over previous
//
#include <hip/hip_runtime.h>

#define BB 8
#define DD 512
#define NPIX 1600
#define KK 64
#define OUTN 4096
#define DKN 32768   // D*K
#define NSPLIT 13   // 13 chunks of 2 n-tiles each (last chunk has 1)

// ---------------------------------------------------------------------------
// K1: scores = conv_w @ feat (per batch, 64x64 n-tiles), fused softmax over K,
//     writes assign2[b][k][n] (k-major, so K2 can stage [k][nn] coalesced) and
//     atomically accumulates asum[b][k] = sum_n assign[b,k,n].
// ---------------------------------------------------------------------------
__global__ __launch_bounds__(256) void k1_scores(
    const float* __restrict__ x, const float* __restrict__ convw,
    float* __restrict__ assign2, float* __restrict__ asum) {
  __shared__ __align__(16) float cws[64 * 68];  // [k][dd], reused as scoreT[n][k]
  __shared__ __align__(16) float xs[64 * 68];   // [dd][nn]
  int t = threadIdx.x;
  int b = blockIdx.y;
  int n0 = blockIdx.x * 64;
  int tn = t & 15, tk = t >> 4;
  int r = t >> 2, c = (t & 3) * 16;
  float acc[4][4] = {};

  for (int d0 = 0; d0 < DD; d0 += 64) {
    const float* cw = convw + (long)r * DD + d0 + c;
    const float* xp = x + ((long)(b * DD + d0 + r)) * NPIX + n0 + c;
#pragma unroll
    for (int q = 0; q < 4; q++) {
      *(float4*)(&cws[r * 68 + c + q * 4]) = *(const float4*)(cw + q * 4);
      *(float4*)(&xs[r * 68 + c + q * 4]) = *(const float4*)(xp + q * 4);
    }
    __syncthreads();
#pragma unroll 4
    for (int dd = 0; dd < 64; ++dd) {
      float a0 = cws[(tk * 4 + 0) * 68 + dd];
      float a1 = cws[(tk * 4 + 1) * 68 + dd];
      float a2 = cws[(tk * 4 + 2) * 68 + dd];
      float a3 = cws[(tk * 4 + 3) * 68 + dd];
      float4 bv = *(const float4*)(&xs[dd * 68 + tn * 4]);
      acc[0][0] += a0 * bv.x; acc[0][1] += a0 * bv.y; acc[0][2] += a0 * bv.z; acc[0][3] += a0 * bv.w;
      acc[1][0] += a1 * bv.x; acc[1][1] += a1 * bv.y; acc[1][2] += a1 * bv.z; acc[1][3] += a1 * bv.w;
      acc[2][0] += a2 * bv.x; acc[2][1] += a2 * bv.y; acc[2][2] += a2 * bv.z; acc[2][3] += a2 * bv.w;
      acc[3][0] += a3 * bv.x; acc[3][1] += a3 * bv.y; acc[3][2] += a3 * bv.z; acc[3][3] += a3 * bv.w;
    }
    __syncthreads();
  }

  // scores -> scoreT[n][k] in LDS (reuse cws)
#pragma unroll
  for (int i = 0; i < 4; i++)
#pragma unroll
    for (int j = 0; j < 4; j++)
      cws[(tn * 4 + j) * 68 + tk * 4 + i] = acc[i][j];
  __syncthreads();

  // softmax over k: 4 lanes cooperate per n (lanes 4n..4n+3, shfl_xor 1,2)
  {
    int n = t >> 2;           // 0..63
    int kq = (t & 3) * 16;    // 0,16,32,48
    float v[16];
    float m = -1e30f;
#pragma unroll
    for (int q = 0; q < 4; q++) {
      float4 s4 = *(const float4*)(&cws[n * 68 + kq + q * 4]);
      v[q * 4 + 0] = s4.x; v[q * 4 + 1] = s4.y;
      v[q * 4 + 2] = s4.z; v[q * 4 + 3] = s4.w;
      m = fmaxf(m, fmaxf(fmaxf(s4.x, s4.y), fmaxf(s4.z, s4.w)));
    }
    m = fmaxf(m, __shfl_xor(m, 1, 64));
    m = fmaxf(m, __shfl_xor(m, 2, 64));
    float ssum = 0.f;
#pragma unroll
    for (int i = 0; i < 16; i++) {
      v[i] = expf(v[i] - m);
      ssum += v[i];
    }
    ssum += __shfl_xor(ssum, 1, 64);
    ssum += __shfl_xor(ssum, 2, 64);
    float inv = 1.0f / ssum;
#pragma unroll
    for (int q = 0; q < 4; q++) {
      float4 o;
      o.x = v[q * 4 + 0] * inv; o.y = v[q * 4 + 1] * inv;
      o.z = v[q * 4 + 2] * inv; o.w = v[q * 4 + 3] * inv;
      *(float4*)(&cws[n * 68 + kq + q * 4]) = o;   // normalized assign[n][k]
    }
  }
  __syncthreads();
  // asum partials: 256 threads, 4 partial atomics per (b,k)
  {
    int k2i = t & 63, ng = t >> 6;
    float s = 0.f;
#pragma unroll
    for (int nn = ng * 16; nn < ng * 16 + 16; nn++) s += cws[nn * 68 + k2i];
    atomicAdd(&asum[b * KK + k2i], s);
  }
  // transposed write: assign2[b][k][n0+n] = assign[n][k]  (coalesced along n)
  {
    int k = t >> 2, g = t & 3;
    float vv[16];
#pragma unroll
    for (int i = 0; i < 16; i++) vv[i] = cws[(g * 16 + i) * 68 + k];
    float* ap = assign2 + ((long)b * KK + k) * NPIX + n0 + g * 16;
#pragma unroll
    for (int q = 0; q < 4; q++) {
      float4 o4 = {vv[q * 4 + 0], vv[q * 4 + 1], vv[q * 4 + 2], vv[q * 4 + 3]};
      *(float4*)(ap + q * 4) = o4;
    }
  }
}

// ---------------------------------------------------------------------------
// K2: vpT[ns][b][k][d] = sum_{n in 2-tile chunk ns} x[b,d,n] * assign[b,k,n]
// Dot-product inner form: both operands as ds_read_b128.
//  - xs: [dd][68] padded (xv reads hit only 4 rows/wave -> 2-way, free)
//  - as_: [k][64] XOR-swizzled col ^= ((k>>2)&7)<<2 (16 rows/wave at 256 B
//    stride would be 8-way conflicted without it)
// ---------------------------------------------------------------------------
__global__ __launch_bounds__(256) void k2_vlad(
    const float* __restrict__ x, const float* __restrict__ assign2,
    float* __restrict__ vpT) {
  __shared__ __align__(16) float xs[64 * 68];   // [dd][nn]
  __shared__ __align__(16) float as_[64 * 64];  // [k][nn] swizzled
  int t = threadIdx.x;
  int dt = blockIdx.x, ns = blockIdx.y, b = blockIdx.z;
  int d0 = dt * 64;
  int tk = t & 15, td = t >> 4;
  int r = t >> 2, c = (t & 3) * 16;
  int sw = (tk & 7) << 2;             // read-side swizzle for rows tk*4+j
  int swr = ((r >> 2) & 7) << 2;      // write-side swizzle for row r
  float acc[4][4] = {};

  for (int cc = 0; cc < 2; cc++) {
    int nt = ns * 2 + cc;
    if (nt >= 25) break;
    int n0 = nt * 64;
    const float* xp = x + ((long)(b * DD + d0 + r)) * NPIX + n0 + c;
    const float* ap = assign2 + ((long)b * KK + r) * NPIX + n0 + c;
#pragma unroll
    for (int q = 0; q < 4; q++) {
      *(float4*)(&xs[r * 68 + c + q * 4]) = *(const float4*)(xp + q * 4);
      *(float4*)(&as_[r * 64 + ((c + q * 4) ^ swr)]) = *(const float4*)(ap + q * 4);
    }
    __syncthreads();
#pragma unroll 2
    for (int nn = 0; nn < 64; nn += 4) {
      float4 xv0 = *(const float4*)(&xs[(td * 4 + 0) * 68 + nn]);
      float4 xv1 = *(const float4*)(&xs[(td * 4 + 1) * 68 + nn]);
      float4 xv2 = *(const float4*)(&xs[(td * 4 + 2) * 68 + nn]);
      float4 xv3 = *(const float4*)(&xs[(td * 4 + 3) * 68 + nn]);
      int nsw = nn ^ sw;
      float4 av0 = *(const float4*)(&as_[(tk * 4 + 0) * 64 + nsw]);
      float4 av1 = *(const float4*)(&as_[(tk * 4 + 1) * 64 + nsw]);
      float4 av2 = *(const float4*)(&as_[(tk * 4 + 2) * 64 + nsw]);
      float4 av3 = *(const float4*)(&as_[(tk * 4 + 3) * 64 + nsw]);
#define DOT4(i, j, XV, AV) \
  acc[i][j] += XV.x * AV.x + XV.y * AV.y + XV.z * AV.z + XV.w * AV.w
      DOT4(0, 0, xv0, av0); DOT4(0, 1, xv0, av1); DOT4(0, 2, xv0, av2); DOT4(0, 3, xv0, av3);
      DOT4(1, 0, xv1, av0); DOT4(1, 1, xv1, av1); DOT4(1, 2, xv1, av2); DOT4(1, 3, xv1, av3);
      DOT4(2, 0, xv2, av0); DOT4(2, 1, xv2, av1); DOT4(2, 2, xv2, av2); DOT4(2, 3, xv2, av3);
      DOT4(3, 0, xv3, av0); DOT4(3, 1, xv3, av1); DOT4(3, 2, xv3, av2); DOT4(3, 3, xv3, av3);
#undef DOT4
    }
    __syncthreads();
  }
  // write transposed partial: vpT[((ns*8+b)*64+k)*512 + d], float4 over d
  float* vp = vpT + (((long)ns * BB + b) * KK) * DD;
#pragma unroll
  for (int j = 0; j < 4; j++) {
    int k = tk * 4 + j;
    float4 o = {acc[0][j], acc[1][j], acc[2][j], acc[3][j]};
    *(float4*)(vp + (long)k * DD + d0 + td * 4) = o;
  }
}

// ---------------------------------------------------------------------------
// K3: reduce 13 partials (unit-stride reads), subtract asum*centers,
// intra-normalize over D per (b,k), write desc[b][d*K+k], accumulate
// global sumsq per b.
// ---------------------------------------------------------------------------
__global__ __launch_bounds__(256) void k3_norm(
    const float* __restrict__ vpT, const float* __restrict__ asum,
    const float* __restrict__ centers, float* __restrict__ desc,
    float* __restrict__ gsq) {
  __shared__ float sred[4];
  int k = blockIdx.x, b = blockIdx.y;
  int t = threadIdx.x;
  float a = asum[b * KK + k];
  float v[2];
#pragma unroll
  for (int h = 0; h < 2; h++) {
    int d = t + h * 256;
    float s = 0.f;
#pragma unroll
    for (int p = 0; p < NSPLIT; p++)
      s += vpT[(((long)p * BB + b) * KK + k) * DD + d];
    s -= a * centers[(long)d * KK + k];
    v[h] = s;
  }
  float ss = v[0] * v[0] + v[1] * v[1];
  for (int off = 32; off > 0; off >>= 1) ss += __shfl_down(ss, off, 64);
  if ((t & 63) == 0) sred[t >> 6] = ss;
  __syncthreads();
  float tot = sred[0] + sred[1] + sred[2] + sred[3];
  float sc = 1.0f / fmaxf(sqrtf(tot), 1e-12f);
#pragma unroll
  for (int h = 0; h < 2; h++) {
    int d = t + h * 256;
    desc[(long)b * DKN + (long)d * KK + k] = v[h] * sc;
  }
  if (t == 0) atomicAdd(&gsq[b], tot * sc * sc);
}

// ---------------------------------------------------------------------------
// K4: whiten GEMM (memory-bound, streams W exactly once = 512 MB).
// grid (512 o-tiles, 2 j-slices); block = 8 out rows x 8 batches.
// Atomic-free: each j-slice writes its own ydot2 half via LDS reduce.
// ---------------------------------------------------------------------------
__global__ __launch_bounds__(256) void k4_whiten(
    const float* __restrict__ desc, const float* __restrict__ W,
    float* __restrict__ ydot2) {
  __shared__ float red[256];
  int t = threadIdx.x;
  long o0 = (long)blockIdx.x * 8;
  int jbase = blockIdx.y * (DKN / 2);  // 16384
  float acc[8][8];  // [oo][bb]
#pragma unroll
  for (int oo = 0; oo < 8; oo++)
#pragma unroll
    for (int bb = 0; bb < 8; bb++) acc[oo][bb] = 0.f;

  const float* wbase = W + o0 * DKN;
  for (int jt = 0; jt < DKN / 2; jt += 1024) {  // 16 iterations
    int j = jbase + jt + t * 4;
    float4 d4[8];
#pragma unroll
    for (int bb = 0; bb < 8; bb++)
      d4[bb] = *(const float4*)(desc + (long)bb * DKN + j);
#pragma unroll
    for (int oo = 0; oo < 8; oo++) {
      float4 w4 = *(const float4*)(wbase + (long)oo * DKN + j);
#pragma unroll
      for (int bb = 0; bb < 8; bb++) {
        acc[oo][bb] += w4.x * d4[bb].x + w4.y * d4[bb].y +
                       w4.z * d4[bb].z + w4.w * d4[bb].w;
      }
    }
  }
  int lane = t & 63, w = t >> 6;
#pragma unroll
  for (int oo = 0; oo < 8; oo++)
#pragma unroll
    for (int bb = 0; bb < 8; bb++) {
      float v = acc[oo][bb];
      for (int off = 32; off > 0; off >>= 1) v += __shfl_down(v, off, 64);
      if (lane == 0) red[w * 64 + oo * 8 + bb] = v;
    }
  __syncthreads();
  if (t < 64) {
    int oo = t >> 3, bb = t & 7;
    float s = red[t] + red[64 + t] + red[128 + t] + red[192 + t];
    ydot2[((long)blockIdx.y * BB + bb) * OUTN + o0 + oo] = s;
  }
}

// ---------------------------------------------------------------------------
// K5: y = (ydot2[0]+ydot2[1])/gnorm + bias; final L2 normalize; write out.
// ---------------------------------------------------------------------------
__global__ __launch_bounds__(256) void k5_final(
    const float* __restrict__ ydot2, const float* __restrict__ gsq,
    const float* __restrict__ bias, float* __restrict__ out) {
  __shared__ float sred[4];
  int b = blockIdx.x, t = threadIdx.x;
  float g = fmaxf(sqrtf(gsq[b]), 1e-12f);
  float inv_g = 1.0f / g;
  float v[16];
  float ss = 0.f;
#pragma unroll
  for (int i = 0; i < 16; i++) {
    int o = t + i * 256;
    float dot = ydot2[(long)b * OUTN + o] + ydot2[((long)BB + b) * OUTN + o];
    float val = dot * inv_g + bias[o];
    v[i] = val;
    ss += val * val;
  }
  for (int off = 32; off > 0; off >>= 1) ss += __shfl_down(ss, off, 64);
  if ((t & 63) == 0) sred[t >> 6] = ss;
  __syncthreads();
  float tot = sred[0] + sred[1] + sred[2] + sred[3];
  float sc = 1.0f / fmaxf(sqrtf(tot), 1e-12f);
#pragma unroll
  for (int i = 0; i < 16; i++) {
    int o = t + i * 256;
    out[(long)b * OUTN + o] = v[i] * sc;
  }
}

extern "C" void kernel_launch(void* const* d_in, const int* in_sizes, int n_in,
                              void* d_out, int out_size, void* d_ws,
                              size_t ws_size, hipStream_t stream) {
  const float* x = (const float*)d_in[0];        // [8,512,40,40]
  const float* convw = (const float*)d_in[1];    // [64,512]
  const float* centers = (const float*)d_in[2];  // [512,64]
  const float* ww = (const float*)d_in[3];       // [4096,32768]
  const float* wb = (const float*)d_in[4];       // [4096]
  float* out = (float*)d_out;                    // [8,4096] f32

  // ws layout (floats):
  float* base = (float*)d_ws;
  float* asum = base;                        // 512
  float* gsq = base + 512;                   // 8
  float* ydot2 = base + 1024;                // 2*8*4096   = 65536
  float* assign2 = base + 66560;             // 8*64*1600  = 819200
  float* desc = assign2;                     // reuse (assign2 dead after k2)
  float* vpT = base + 66560 + 819200;        // 13*8*64*512 = 3407872

  // zero only the atomic accumulators (asum, gsq)
  hipMemsetAsync(base, 0, 520 * sizeof(float), stream);

  hipLaunchKernelGGL(k1_scores, dim3(25, 8), dim3(256), 0, stream, x, convw,
                     assign2, asum);
  hipLaunchKernelGGL(k2_vlad, dim3(8, NSPLIT, 8), dim3(256), 0, stream, x,
                     assign2, vpT);
  hipLaunchKernelGGL(k3_norm, dim3(64, 8), dim3(256), 0, stream, vpT, asum,
                     centers, desc, gsq);
  hipLaunchKernelGGL(k4_whiten, dim3(512, 2), dim3(256), 0, stream, desc, ww,
                     ydot2);
  hipLaunchKernelGGL(k5_final, dim3(8), dim3(256), 0, stream, ydot2, gsq, wb,
                     out);
}